// Round 1
// baseline (379.014 us; speedup 1.0000x reference)
//
#include <hip/hip_runtime.h>
#include <hip/hip_bf16.h>

#define NPG 9
#define DH 64
#define DIN 11
#define GPB 28            // graphs per block
#define APB (GPB*NPG)     // 252 active node-threads
#define TPB 256
#define NGRAPH 65536
#define NNODE (NGRAPH*NPG)

// transposed weights, written by prep_kernel every launch (same work each call)
__device__ float g_winT[DIN*DH];   // [k][f] = W_in[f][k]
__device__ float g_rel1T[DH*DH];   // [g][f] = W1_rel[f][g]
__device__ float g_m1T[DH*DH];     // [g][f] = W1_root[f][g] - W1_rel[f][g]
__device__ float g_rel2T[DH*DH];
__device__ float g_m2T[DH*DH];

__global__ void prep_kernel(const float* __restrict__ W_in,
                            const float* __restrict__ W1_rel,
                            const float* __restrict__ W1_root,
                            const float* __restrict__ W2_rel,
                            const float* __restrict__ W2_root) {
  int idx = blockIdx.x*blockDim.x + threadIdx.x;
  if (idx < DIN*DH) { int k = idx/DH, f = idx - k*DH; g_winT[idx] = W_in[f*DIN+k]; }
  if (idx < DH*DH) {
    int g = idx/DH, f = idx - g*DH;
    float r1 = W1_rel[f*DH+g];
    float r2 = W2_rel[f*DH+g];
    g_rel1T[idx] = r1;
    g_m1T [idx] = W1_root[f*DH+g] - r1;
    g_rel2T[idx] = r2;
    g_m2T [idx] = W2_root[f*DH+g] - r2;
  }
}

__device__ __forceinline__ float fast_tanh(float v) {
  // tanh(v) = 1 - 2/(exp(2v)+1); exp->inf gives +1, exp->0 gives -1 (safe)
  float e = __expf(2.f*v);
  return 1.f - 2.f*__builtin_amdgcn_rcpf(e + 1.f);
}

__global__ __launch_bounds__(TPB, 3) void fused_kernel(
    const float* __restrict__ x,
    const float* __restrict__ b_in,
    const float* __restrict__ b1,
    const float* __restrict__ b2,
    const float* __restrict__ Whead,   // [8][64][2]
    const float* __restrict__ bhead,   // [8][2]
    float* __restrict__ out)           // [B*8 loc][B*8 scale]
{
  // bf16 h staging: stride 66 shorts -> bank = (33*tid + g/2)%32, conflict-free
  __shared__ __align__(16) __hip_bfloat16 hstage[TPB][DH+2];
  __shared__ float sS [GPB+2][DH+1];   // per-graph feature sums
  __shared__ float szS[GPB+2][DH+1];   // shared S @ W_rel^T

  const int tid = threadIdx.x;
  const int gl  = tid / NPG;           // local graph (0..28)
  const int nn  = tid - gl*NPG;        // node within graph (0..8)
  const int graph = blockIdx.x*GPB + gl;
  const bool act = (gl < GPB) && (graph < NGRAPH);

  // ---- cooperative, coalesced x stage (reuse hstage memory as float) ----
  float* xs = reinterpret_cast<float*>(&hstage[0][0]);  // 2772 floats <= 33792B
  {
    const long long base = (long long)blockIdx.x * (APB*DIN);
    for (int i = tid; i < APB*DIN; i += TPB) {
      long long gi = base + i;
      xs[i] = (gi < (long long)NNODE*DIN) ? x[gi] : 0.f;
    }
  }
  __syncthreads();
  float xr[DIN];
  #pragma unroll
  for (int k = 0; k < DIN; ++k)
    xr[k] = (tid < APB) ? xs[tid*DIN + k] : 0.f;
  __syncthreads();   // done with xs before hstage reuse

  // ---- input layer: z = x @ W_in^T + b_in (weights via s_load, uniform) ----
  float z[DH];
  #pragma unroll
  for (int f = 0; f < DH; ++f) z[f] = b_in[f];
  #pragma unroll
  for (int k = 0; k < DIN; ++k) {
    const float s = xr[k];
    const float* __restrict__ w = &g_winT[k*DH];
    #pragma unroll
    for (int f = 0; f < DH; ++f) z[f] += s*w[f];
  }

  // ---- one GraphConv layer: z <- tanh(S@rT + h@mT + bias), h = current z ----
  auto conv_layer = [&](const float* __restrict__ rT,
                        const float* __restrict__ mT,
                        const float* __restrict__ bias) {
    // stage h as bf16
    #pragma unroll
    for (int f = 0; f < DH; ++f) hstage[tid][f] = __float2bfloat16(z[f]);
    __syncthreads();
    // S-phase: 28*64 = 1792 sums, 7 per thread
    #pragma unroll
    for (int r = 0; r < 7; ++r) {
      int t = r*TPB + tid;
      int f = t / GPB;
      int grp = t - f*GPB;
      float s = 0.f;
      #pragma unroll
      for (int j = 0; j < NPG; ++j) s += __bfloat162float(hstage[grp*NPG + j][f]);
      sS[grp][f] = s;
    }
    __syncthreads();
    // zS-phase: zS[grp][f] = dot(S[grp][:], W_rel^T[:,f]) -- shared, not 9x redundant
    #pragma unroll
    for (int r = 0; r < 7; ++r) {
      int t = r*TPB + tid;
      int f = t / GPB;
      int grp = t - f*GPB;
      float a0 = 0.f, a1 = 0.f;
      #pragma unroll 4
      for (int g = 0; g < DH; g += 2) {
        a0 += sS[grp][g]   * rT[ g   *DH + f];
        a1 += sS[grp][g+1] * rT[(g+1)*DH + f];
      }
      szS[grp][f] = a0 + a1;
    }
    __syncthreads();
    // per-node matvec: z[f] = zS + bias + sum_g h[g]*M^T[g][f]; weights via s_load
    #pragma unroll
    for (int f = 0; f < DH; ++f) z[f] = szS[gl][f] + bias[f];
    for (int g = 0; g < DH; ++g) {
      const float hg = __bfloat162float(hstage[tid][g]);
      const float* __restrict__ w = &mT[g*DH];
      #pragma unroll
      for (int f = 0; f < DH; ++f) z[f] += hg * w[f];
    }
    #pragma unroll
    for (int f = 0; f < DH; ++f) z[f] = fast_tanh(z[f]);
    __syncthreads();   // protect hstage before next layer's restage
  };

  conv_layer(g_rel1T, g_m1T, b1);
  conv_layer(g_rel2T, g_m2T, b2);

  // ---- head: nodes 1..8 -> (loc, scale) ----
  if (act && nn > 0) {
    const int p = nn - 1;
    const float* __restrict__ wh = Whead + p*(DH*2);
    float lo = bhead[p*2+0];
    float sc = bhead[p*2+1];
    #pragma unroll
    for (int g = 0; g < DH; ++g) {
      lo += z[g]*wh[2*g];
      sc += z[g]*wh[2*g+1];
    }
    float t  = sc + 0.5413248546129181f;   // log(expm1(1))
    float e  = __expf(t);
    float sp = (t > 15.f) ? t : __logf(1.f + e);
    sp = fmaxf(sp, 1e-4f);
    const long long o = (long long)graph*8 + p;
    out[o] = lo;
    out[(long long)NGRAPH*8 + o] = sp;
  }
}

extern "C" void kernel_launch(void* const* d_in, const int* in_sizes, int n_in,
                              void* d_out, int out_size, void* d_ws, size_t ws_size,
                              hipStream_t stream) {
  const float* x       = (const float*)d_in[0];
  // d_in[1] = edge_index: structure is known (full 9-clique), unused
  const float* W_in    = (const float*)d_in[2];
  const float* b_in    = (const float*)d_in[3];
  const float* W1_rel  = (const float*)d_in[4];
  const float* b1      = (const float*)d_in[5];
  const float* W1_root = (const float*)d_in[6];
  const float* W2_rel  = (const float*)d_in[7];
  const float* b2      = (const float*)d_in[8];
  const float* W2_root = (const float*)d_in[9];
  const float* Whead   = (const float*)d_in[10];
  const float* bhead   = (const float*)d_in[11];
  float* out = (float*)d_out;

  hipLaunchKernelGGL(prep_kernel, dim3(16), dim3(TPB), 0, stream,
                     W_in, W1_rel, W1_root, W2_rel, W2_root);
  const int nblk = (NGRAPH + GPB - 1)/GPB;
  hipLaunchKernelGGL(fused_kernel, dim3(nblk), dim3(TPB), 0, stream,
                     x, b_in, b1, b2, Whead, bhead, out);
}

// Round 2
// 227.214 us; speedup vs baseline: 1.6681x; 1.6681x over previous
//
#include <hip/hip_runtime.h>
#include <hip/hip_bf16.h>

#define NPG 9
#define DH 64
#define DIN 11
#define GPB 32
#define ROWS (GPB*NPG)        // 288
#define TPB 576               // 9 waves
#define NGRAPH 65536
#define NBLK (NGRAPH/GPB)     // 2048
#define OUT_HALF ((long long)NGRAPH*8)

typedef __attribute__((ext_vector_type(8))) short short8;
typedef __attribute__((ext_vector_type(4))) float f32x4;

// weight staging, rewritten by prep_kernel every launch
__device__ float g_winT[DIN*DH];     // [k][f] = W_in[f][k]
__device__ short g_bfrag1[16*512];   // conv1 B-fragments (kk*4+nt), bf16 bits
__device__ short g_bfrag2[16*512];   // conv2
__device__ short g_bfragH[2*512];    // head B-fragments (kk), N=16

__device__ __forceinline__ short f2b(float f) {   // fp32 -> bf16 bits, RTN-even
  unsigned u = __builtin_bit_cast(unsigned, f);
  u += 0x7fffu + ((u >> 16) & 1u);
  return (short)(u >> 16);
}
__device__ __forceinline__ float b2f(short s) {
  unsigned u = ((unsigned)(unsigned short)s) << 16;
  return __builtin_bit_cast(float, u);
}
__device__ __forceinline__ float fast_tanh(float v) {
  float e = __expf(2.f*v);
  return 1.f - 2.f*__builtin_amdgcn_rcpf(e + 1.f);
}

// B2 = [M^T ; rel^T] (128x64), M = W_root - W_rel. Fragment order: lane l holds
// B[k = kk*32 + (l>>4)*8 + j][n = nt*16 + (l&15)], j=0..7 contiguous.
__global__ void prep_kernel(const float* __restrict__ W_in,
                            const float* __restrict__ W1_rel, const float* __restrict__ W1_root,
                            const float* __restrict__ W2_rel, const float* __restrict__ W2_root,
                            const float* __restrict__ W_head) {
  int idx = blockIdx.x*blockDim.x + threadIdx.x;
  if (idx < DIN*DH) {
    int k = idx >> 6, f = idx & 63;
    g_winT[idx] = W_in[f*DIN + k];
  }
  if (idx < 16*512) {
    int frag = idx >> 9, kk = frag >> 2, nt = frag & 3;
    int l = (idx >> 3) & 63, j = idx & 7;
    int k2 = kk*32 + ((l >> 4) << 3) + j;       // 0..127
    int n  = nt*16 + (l & 15);                  // 0..63
    float v1, v2;
    if (k2 < 64) {
      v1 = W1_root[n*DH + k2] - W1_rel[n*DH + k2];
      v2 = W2_root[n*DH + k2] - W2_rel[n*DH + k2];
    } else {
      v1 = W1_rel[n*DH + k2 - 64];
      v2 = W2_rel[n*DH + k2 - 64];
    }
    g_bfrag1[idx] = f2b(v1);
    g_bfrag2[idx] = f2b(v2);
  }
  if (idx < 2*512) {
    int kk = idx >> 9;
    int l = (idx >> 3) & 63, j = idx & 7;
    int k = kk*32 + ((l >> 4) << 3) + j;        // 0..63
    int n = l & 15;                             // p = n>>1, oc = n&1
    g_bfragH[idx] = f2b(W_head[(n >> 1)*(DH*2) + k*2 + (n & 1)]);
  }
}

// Hs swizzle: feature chunk c (8 bf16 = 16B) of row r stored at chunk c^(r&7).
#define HS_OFF(r, c) ((r)*64 + (((c) ^ ((r) & 7)) << 3))

__global__ __launch_bounds__(TPB) void fused_kernel(
    const float* __restrict__ x,
    const float* __restrict__ b_in,
    const float* __restrict__ b1,
    const float* __restrict__ b2,
    const float* __restrict__ bhead,
    float* __restrict__ out)
{
  __shared__ short Hs[ROWS*64];                          // 36864 B, swizzled bf16
  __shared__ union { float xs[ROWS*13]; short ss[GPB*64]; } u;  // 14976 B

  const int tid  = threadIdx.x;
  const int lane = tid & 63;
  const int wave = tid >> 6;          // 0..8
  const int l15  = lane & 15;
  const int kgrp = lane >> 4;         // 0..3

  // ---- stage x (coalesced), fp32, stride-13 to dodge bank conflicts ----
  {
    const float* __restrict__ xsrc = x + (size_t)blockIdx.x * (ROWS*DIN);
    for (int i = tid; i < ROWS*DIN; i += TPB) {
      int r = (int)(((unsigned)i * 2979u) >> 15);   // i/11 exact for i<3168
      int c = i - r*DIN;
      u.xs[r*13 + c] = xsrc[i];
    }
  }
  __syncthreads();

  // ---- input layer: per-thread fp32 matvec (wave-uniform s_load weights) ----
  if (tid < ROWS) {
    const int row = tid;
    float xr[DIN];
    #pragma unroll
    for (int k = 0; k < DIN; ++k) xr[k] = u.xs[row*13 + k];
    float z[DH];
    #pragma unroll
    for (int f = 0; f < DH; ++f) z[f] = b_in[f];
    #pragma unroll
    for (int k = 0; k < DIN; ++k) {
      const float s = xr[k];
      const float* __restrict__ w = &g_winT[k*DH];
      #pragma unroll
      for (int f = 0; f < DH; ++f) z[f] += s * w[f];
    }
    #pragma unroll
    for (int c = 0; c < 8; ++c) {
      short8 v;
      #pragma unroll
      for (int j = 0; j < 8; ++j) v[j] = f2b(z[c*8 + j]);
      *(short8*)&Hs[HS_OFF(row, c)] = v;
    }
  }
  __syncthreads();

  // ---- one conv layer: z = tanh([h|S] @ [M^T;rel^T] + b), all via MFMA ----
  auto layer = [&](const short* __restrict__ bfrag, const float* __restrict__ bias) {
    // S-phase: S[g][f] = sum of 9 node rows (fp32 acc, bf16 store)
    if (tid < 256) {
      const int g = tid >> 3, fc = tid & 7;
      float s[8] = {0,0,0,0,0,0,0,0};
      #pragma unroll
      for (int j = 0; j < NPG; ++j) {
        const int r = g*NPG + j;
        short8 v = *(const short8*)&Hs[HS_OFF(r, fc)];
        #pragma unroll
        for (int e = 0; e < 8; ++e) s[e] += b2f(v[e]);
      }
      short8 o;
      #pragma unroll
      for (int e = 0; e < 8; ++e) o[e] = f2b(s[e]);
      *(short8*)&u.ss[g*64 + ((fc ^ (g & 7)) << 3)] = o;
    }
    __syncthreads();

    // B fragments: 16 x global_load_dwordx4 (L1-broadcast across waves)
    short8 B[4][4];
    #pragma unroll
    for (int kk = 0; kk < 4; ++kk)
      #pragma unroll
      for (int nt = 0; nt < 4; ++nt)
        B[kk][nt] = *(const short8*)&bfrag[((kk << 2) + nt)*512 + lane*8];

    float bias_c[4];
    #pragma unroll
    for (int nt = 0; nt < 4; ++nt) bias_c[nt] = bias[nt*16 + l15];

    f32x4 acc[2][4];
    #pragma unroll
    for (int tt = 0; tt < 2; ++tt)
      #pragma unroll
      for (int nt = 0; nt < 4; ++nt) acc[tt][nt] = (f32x4){0.f,0.f,0.f,0.f};

    // GEMM: wave w owns row-tiles 2w, 2w+1; K=128 virtual (kk 0,1: h; kk 2,3: S)
    #pragma unroll
    for (int tt = 0; tt < 2; ++tt) {
      const int row = (2*wave + tt)*16 + l15;      // A row
      const int g   = (row*57) >> 9;               // row/9 exact for row<288
      short8 A[4];
      #pragma unroll
      for (int kk = 0; kk < 2; ++kk)
        A[kk] = *(const short8*)&Hs[HS_OFF(row, kk*4 + kgrp)];
      #pragma unroll
      for (int kk = 2; kk < 4; ++kk)
        A[kk] = *(const short8*)&u.ss[g*64 + ((((kk - 2)*4 + kgrp) ^ (g & 7)) << 3)];
      #pragma unroll
      for (int kk = 0; kk < 4; ++kk)
        #pragma unroll
        for (int nt = 0; nt < 4; ++nt)
          acc[tt][nt] = __builtin_amdgcn_mfma_f32_16x16x32_bf16(A[kk], B[kk][nt], acc[tt][nt], 0, 0, 0);
    }
    __syncthreads();   // all Hs/ss reads done before overwrite

    // epilogue: bias + tanh + bf16 write-back (C: col=lane&15, row=(lane>>4)*4+reg)
    #pragma unroll
    for (int tt = 0; tt < 2; ++tt) {
      #pragma unroll
      for (int nt = 0; nt < 4; ++nt) {
        #pragma unroll
        for (int reg = 0; reg < 4; ++reg) {
          const int row = (2*wave + tt)*16 + kgrp*4 + reg;
          const int col = nt*16 + l15;
          float v = acc[tt][nt][reg] + bias_c[nt];
          v = fast_tanh(v);
          Hs[row*64 + (((col >> 3) ^ (row & 7)) << 3) + (col & 7)] = f2b(v);
        }
      }
    }
    __syncthreads();
  };

  layer(g_bfrag1, b1);
  layer(g_bfrag2, b2);

  // ---- head: [288 x 64] @ [64 x 16] MFMA, predicated scatter stores ----
  short8 HB[2];
  #pragma unroll
  for (int kk = 0; kk < 2; ++kk)
    HB[kk] = *(const short8*)&g_bfragH[kk*512 + lane*8];

  const int p  = l15 >> 1;
  const int oc = l15 & 1;
  const float bh = bhead[p*2 + oc];

  #pragma unroll
  for (int tt = 0; tt < 2; ++tt) {
    const int t = 2*wave + tt;
    const int arow = t*16 + l15;
    f32x4 hacc = (f32x4){0.f,0.f,0.f,0.f};
    #pragma unroll
    for (int kk = 0; kk < 2; ++kk) {
      short8 A = *(const short8*)&Hs[HS_OFF(arow, kk*4 + kgrp)];
      hacc = __builtin_amdgcn_mfma_f32_16x16x32_bf16(A, HB[kk], hacc, 0, 0, 0);
    }
    #pragma unroll
    for (int reg = 0; reg < 4; ++reg) {
      const int row = t*16 + kgrp*4 + reg;
      const int g   = (row*57) >> 9;
      const int nn  = row - g*NPG;             // node within graph
      if (nn == p + 1) {                       // this lane's head position
        const float v = hacc[reg] + bh;
        const long long gg = (long long)blockIdx.x * GPB + g;
        if (oc == 0) {
          out[gg*8 + p] = v;
        } else {
          float tv = v + 0.5413248546129181f;  // log(expm1(1))
          float e  = __expf(tv);
          float sp = (tv > 15.f) ? tv : __logf(1.f + e);
          out[OUT_HALF + gg*8 + p] = fmaxf(sp, 1e-4f);
        }
      }
    }
  }
}

extern "C" void kernel_launch(void* const* d_in, const int* in_sizes, int n_in,
                              void* d_out, int out_size, void* d_ws, size_t ws_size,
                              hipStream_t stream) {
  const float* x       = (const float*)d_in[0];
  // d_in[1] = edge_index: full 9-clique structure is compile-time, unused
  const float* W_in    = (const float*)d_in[2];
  const float* b_in    = (const float*)d_in[3];
  const float* W1_rel  = (const float*)d_in[4];
  const float* b1      = (const float*)d_in[5];
  const float* W1_root = (const float*)d_in[6];
  const float* W2_rel  = (const float*)d_in[7];
  const float* b2      = (const float*)d_in[8];
  const float* W2_root = (const float*)d_in[9];
  const float* Whead   = (const float*)d_in[10];
  const float* bhead   = (const float*)d_in[11];
  float* out = (float*)d_out;

  hipLaunchKernelGGL(prep_kernel, dim3(32), dim3(256), 0, stream,
                     W_in, W1_rel, W1_root, W2_rel, W2_root, Whead);
  hipLaunchKernelGGL(fused_kernel, dim3(NBLK), dim3(TPB), 0, stream,
                     x, b_in, b1, b2, bhead, out);
}

// Round 3
// 226.685 us; speedup vs baseline: 1.6720x; 1.0023x over previous
//
#include <hip/hip_runtime.h>
#include <hip/hip_bf16.h>

#define NPG 9
#define DH 64
#define DIN 11
#define GPB 28
#define ROWS (GPB*NPG)            // 252
#define TPB 256
#define NGRAPH 65536
#define NROWTOT (NGRAPH*NPG)      // 589824
#define NBLK ((NGRAPH + GPB - 1)/GPB)   // 2341
#define OUT_HALF ((long long)NGRAPH*8)

typedef __attribute__((ext_vector_type(8))) short short8;
typedef __attribute__((ext_vector_type(4))) short short4v;
typedef __attribute__((ext_vector_type(4))) float f32x4;

// weight staging, rewritten by prep_kernel every launch
__device__ float g_c1[DH];          // folded conv1 bias
__device__ short g_bfrag1[4*512];   // conv1 B-frags: K=32 = [Wa(11)+pad | Wb(11)+pad]
__device__ short g_bfrag2[16*512];  // conv2 B-frags: K=128 = [M2 | rel2]
__device__ short g_bfragH[2*512];   // head B-frags: K=64, N=16

__device__ __forceinline__ short f2bs(float f) {
  __hip_bfloat16 h = __float2bfloat16(f);   // RTN-even, single cvt instr
  return __builtin_bit_cast(short, h);
}
__device__ __forceinline__ float b2f(short s) {
  unsigned u = ((unsigned)(unsigned short)s) << 16;
  return __builtin_bit_cast(float, u);
}
__device__ __forceinline__ float fast_tanh(float v) {
  float e = __expf(2.f*v);
  return 1.f - 2.f*__builtin_amdgcn_rcpf(e + 1.f);
}

// Fragment convention (16x16x32 bf16): lane l holds A/B[k = (l>>4)*8 + j][...],
// j=0..7 contiguous; B col n = nt*16 + (l&15).
__global__ void prep_kernel(const float* __restrict__ W_in, const float* __restrict__ b_in,
                            const float* __restrict__ W1_rel, const float* __restrict__ b1,
                            const float* __restrict__ W1_root,
                            const float* __restrict__ W2_rel, const float* __restrict__ W2_root,
                            const float* __restrict__ W_head) {
  __shared__ float Wa[DH][DIN+1], Wb[DH][DIN+1];
  const int tid = threadIdx.x;
  // composite conv1 weights: Wa = (root-rel)@W_in, Wb = rel@W_in  (both [64][11])
  for (int t = tid; t < DH*DIN; t += 1024) {
    int n = t / DIN, k = t - n*DIN;
    float a = 0.f, b = 0.f;
    for (int m = 0; m < DH; ++m) {
      float wi = W_in[m*DIN + k];
      float r  = W1_rel[n*DH + m];
      a += (W1_root[n*DH + m] - r) * wi;
      b += r * wi;
    }
    Wa[n][k] = a; Wb[n][k] = b;
  }
  if (tid < DH) {   // c1 = b1 + (root + 8*rel) @ b_in
    float c = b1[tid];
    for (int m = 0; m < DH; ++m)
      c += (W1_root[tid*DH + m] + 8.f*W1_rel[tid*DH + m]) * b_in[m];
    g_c1[tid] = c;
  }
  __syncthreads();
  for (int i = tid; i < 4*512; i += 1024) {       // conv1 frags
    int nt = i >> 9;
    int l = (i >> 3) & 63, j = i & 7;
    int k = ((l >> 4) << 3) + j;                  // 0..31
    int n = nt*16 + (l & 15);
    float v = 0.f;
    if (k < 16) { if (k < DIN) v = Wa[n][k]; }
    else        { if (k - 16 < DIN) v = Wb[n][k - 16]; }
    g_bfrag1[i] = f2bs(v);
  }
  for (int i = tid; i < 16*512; i += 1024) {      // conv2 frags
    int frag = i >> 9, kk = frag >> 2, nt = frag & 3;
    int l = (i >> 3) & 63, j = i & 7;
    int k2 = kk*32 + ((l >> 4) << 3) + j;         // 0..127
    int n  = nt*16 + (l & 15);
    float v = (k2 < 64) ? (W2_root[n*DH + k2] - W2_rel[n*DH + k2])
                        : W2_rel[n*DH + k2 - 64];
    g_bfrag2[i] = f2bs(v);
  }
  for (int i = tid; i < 2*512; i += 1024) {       // head frags
    int kk = i >> 9;
    int l = (i >> 3) & 63, j = i & 7;
    int k = kk*32 + ((l >> 4) << 3) + j;          // 0..63
    int n = l & 15;                               // p=n>>1, oc=n&1
    g_bfragH[i] = f2bs(W_head[(n >> 1)*(DH*2) + k*2 + (n & 1)]);
  }
}

// Hs swizzle: 16B chunk c of row r stored at chunk c^(r&7)
#define HS_W(r, col) ((r)*64 + (((((col) >> 3)) ^ ((r) & 7)) << 3) + ((col) & 7))
#define HS_CH(r, c)  ((r)*64 + (((c) ^ ((r) & 7)) << 3))

__global__ __launch_bounds__(TPB, 4) void fused_kernel(
    const float* __restrict__ x,
    const float* __restrict__ b2,
    const float* __restrict__ bhead,
    float* __restrict__ out)
{
  __shared__ short Hs[ROWS*DH];                     // 32256 B
  __shared__ union {
    struct { short xs[ROWS*12]; short Sx[GPB*12]; } a;   // 6720 B
    short ss[GPB*64];                                    // 3584 B
  } U;                                              // total LDS 38976 -> 4 blocks/CU

  const int tid  = threadIdx.x;
  const int lane = tid & 63;
  const int wave = tid >> 6;       // 0..3
  const int l15  = lane & 15;
  const int kgrp = lane >> 4;      // 0..3

  short* xs = U.a.xs;
  short* Sx = U.a.Sx;
  short* ss = U.ss;

  // ---- stage x -> bf16 [252][12], col 11 zeroed ----
  {
    const long long base = (long long)blockIdx.x * (ROWS*DIN);
    long long rem = (long long)NROWTOT*DIN - base;
    const int lim = rem < (ROWS*DIN) ? (int)rem : (ROWS*DIN);
    for (int i = tid; i < lim; i += TPB) {
      int r = (int)(((unsigned)i * 2979u) >> 15);   // i/11 exact for i<2772
      int c = i - r*DIN;
      xs[r*12 + c] = f2bs(x[base + i]);
    }
    if (tid < ROWS) xs[tid*12 + 11] = 0;
  }
  __syncthreads();                                  // b1

  // ---- Sx phase: per-graph sum of raw x (bf16), 56 tasks ----
  if (tid < GPB*2) {
    const int g = tid >> 1, half = tid & 1;
    const int rbase = g*NPG;
    float s[8] = {0,0,0,0,0,0,0,0};
    for (int j = 0; j < NPG; ++j) {
      const short* p = &xs[(rbase + j)*12 + half*8];
      short4v a = *(const short4v*)p;
      short4v b = *(const short4v*)(p + 4);   // half==1: garbage, discarded below
      s[0] += b2f(a[0]); s[1] += b2f(a[1]); s[2] += b2f(a[2]); s[3] += b2f(a[3]);
      s[4] += b2f(b[0]); s[5] += b2f(b[1]); s[6] += b2f(b[2]); s[7] += b2f(b[3]);
    }
    short4v o0;
    o0[0] = f2bs(s[0]); o0[1] = f2bs(s[1]); o0[2] = f2bs(s[2]); o0[3] = f2bs(s[3]);
    *(short4v*)&Sx[g*12 + half*8] = o0;       // half0: 0..3, half1: 8..11 (11 stays 0)
    if (!half) {
      short4v o1;
      o1[0] = f2bs(s[4]); o1[1] = f2bs(s[5]); o1[2] = f2bs(s[6]); o1[3] = f2bs(s[7]);
      *(short4v*)&Sx[g*12 + 4] = o1;
    }
  }
  __syncthreads();                                  // b2

  // ---- conv1: z = tanh([x|Sx] @ [Wa;Wb]^T + c1), ONE MFMA per (tile,nt) ----
  {
    short8 B1[4];
    #pragma unroll
    for (int nt = 0; nt < 4; ++nt) B1[nt] = *(const short8*)&g_bfrag1[nt*512 + lane*8];
    float c1v[4];
    #pragma unroll
    for (int nt = 0; nt < 4; ++nt) c1v[nt] = g_c1[nt*16 + l15];

    const int sel = kgrp & 1;
    #pragma unroll
    for (int i = 0; i < 4; ++i) {
      const int t = wave*4 + i;
      int row = t*16 + l15; if (row > ROWS-1) row = ROWS-1;
      const int g = (row*57) >> 9;                 // row/9 exact for row<288
      const short* bp = (kgrp < 2) ? &xs[row*12] : &Sx[g*12];
      short4v lo = *(const short4v*)(bp + sel*8);  // sel0: k 0..3 | sel1: k 8..11
      short4v hi = *(const short4v*)(bp + 4);      // k 4..7 (sel0 only)
      short8 A;
      A[0] = lo[0]; A[1] = lo[1]; A[2] = lo[2]; A[3] = lo[3];
      A[4] = sel ? (short)0 : hi[0];
      A[5] = sel ? (short)0 : hi[1];
      A[6] = sel ? (short)0 : hi[2];
      A[7] = sel ? (short)0 : hi[3];
      f32x4 acc[4];
      #pragma unroll
      for (int nt = 0; nt < 4; ++nt)
        acc[nt] = (f32x4){c1v[nt], c1v[nt], c1v[nt], c1v[nt]};
      #pragma unroll
      for (int nt = 0; nt < 4; ++nt)
        acc[nt] = __builtin_amdgcn_mfma_f32_16x16x32_bf16(A, B1[nt], acc[nt], 0, 0, 0);
      #pragma unroll
      for (int nt = 0; nt < 4; ++nt) {
        #pragma unroll
        for (int reg = 0; reg < 4; ++reg) {
          const int orow = t*16 + kgrp*4 + reg;
          if (orow < ROWS) {
            const int col = nt*16 + l15;
            Hs[HS_W(orow, col)] = f2bs(fast_tanh(acc[nt][reg]));
          }
        }
      }
    }
  }
  __syncthreads();                                  // b3 (also: xs/Sx dead now)

  // ---- S-phase: per-graph sums of h (bf16), graph-major for bank spread ----
  if (tid < GPB*8) {                                // 224 tasks
    const int fc = (int)(((unsigned)tid * 2341u) >> 16);   // tid/28
    const int g  = tid - fc*GPB;
    float s[8] = {0,0,0,0,0,0,0,0};
    for (int j = 0; j < NPG; ++j) {
      const int r = g*NPG + j;
      short8 v = *(const short8*)&Hs[HS_CH(r, fc)];
      #pragma unroll
      for (int e = 0; e < 8; ++e) s[e] += b2f(v[e]);
    }
    short8 o;
    #pragma unroll
    for (int e = 0; e < 8; ++e) o[e] = f2bs(s[e]);
    *(short8*)&ss[g*64 + ((fc ^ (g & 7)) << 3)] = o;
  }
  __syncthreads();                                  // b4

  // ---- conv2: z = tanh([h|S] @ [M2;rel2]^T + b2), K=128 ----
  {
    short8 B2[4][4];
    #pragma unroll
    for (int kk = 0; kk < 4; ++kk)
      #pragma unroll
      for (int nt = 0; nt < 4; ++nt)
        B2[kk][nt] = *(const short8*)&g_bfrag2[((kk << 2) + nt)*512 + lane*8];
    float b2v[4];
    #pragma unroll
    for (int nt = 0; nt < 4; ++nt) b2v[nt] = b2[nt*16 + l15];

    #pragma unroll
    for (int i = 0; i < 4; ++i) {
      const int t = wave*4 + i;
      int row = t*16 + l15; if (row > ROWS-1) row = ROWS-1;
      const int g = (row*57) >> 9;
      short8 A[4];
      A[0] = *(const short8*)&Hs[HS_CH(row, 0 + kgrp)];
      A[1] = *(const short8*)&Hs[HS_CH(row, 4 + kgrp)];
      A[2] = *(const short8*)&ss[g*64 + (((0 + kgrp) ^ (g & 7)) << 3)];
      A[3] = *(const short8*)&ss[g*64 + (((4 + kgrp) ^ (g & 7)) << 3)];
      f32x4 acc[4];
      #pragma unroll
      for (int nt = 0; nt < 4; ++nt)
        acc[nt] = (f32x4){b2v[nt], b2v[nt], b2v[nt], b2v[nt]};
      #pragma unroll
      for (int kk = 0; kk < 4; ++kk)
        #pragma unroll
        for (int nt = 0; nt < 4; ++nt)
          acc[nt] = __builtin_amdgcn_mfma_f32_16x16x32_bf16(A[kk], B2[kk][nt], acc[nt], 0, 0, 0);
      #pragma unroll
      for (int nt = 0; nt < 4; ++nt) {
        #pragma unroll
        for (int reg = 0; reg < 4; ++reg) {
          const int orow = t*16 + kgrp*4 + reg;
          if (orow < ROWS) {
            const int col = nt*16 + l15;
            Hs[HS_W(orow, col)] = f2bs(fast_tanh(acc[nt][reg]));
          }
        }
      }
    }
  }
  __syncthreads();                                  // b5 (cross-lane Hs handoff)

  // ---- head: [rows x 64] @ [64 x 16] MFMA, predicated scatter stores ----
  {
    short8 HB0 = *(const short8*)&g_bfragH[lane*8];
    short8 HB1 = *(const short8*)&g_bfragH[512 + lane*8];
    const int p  = l15 >> 1;
    const int oc = l15 & 1;
    const float bh = bhead[p*2 + oc];
    #pragma unroll
    for (int i = 0; i < 4; ++i) {
      const int t = wave*4 + i;
      int row = t*16 + l15; if (row > ROWS-1) row = ROWS-1;
      short8 A0 = *(const short8*)&Hs[HS_CH(row, 0 + kgrp)];
      short8 A1 = *(const short8*)&Hs[HS_CH(row, 4 + kgrp)];
      f32x4 acc = (f32x4){bh, bh, bh, bh};
      acc = __builtin_amdgcn_mfma_f32_16x16x32_bf16(A0, HB0, acc, 0, 0, 0);
      acc = __builtin_amdgcn_mfma_f32_16x16x32_bf16(A1, HB1, acc, 0, 0, 0);
      #pragma unroll
      for (int reg = 0; reg < 4; ++reg) {
        const int orow = t*16 + kgrp*4 + reg;
        if (orow < ROWS) {
          const int g  = (orow*57) >> 9;
          const int nn = orow - g*NPG;
          const long long gg = (long long)blockIdx.x*GPB + g;
          if (nn == p + 1 && gg < NGRAPH) {
            const float v = acc[reg];
            if (oc == 0) {
              out[gg*8 + p] = v;
            } else {
              float tv = v + 0.5413248546129181f;   // log(expm1(1))
              float e  = __expf(tv);
              float sp = (tv > 15.f) ? tv : __logf(1.f + e);
              out[OUT_HALF + gg*8 + p] = fmaxf(sp, 1e-4f);
            }
          }
        }
      }
    }
  }
}

extern "C" void kernel_launch(void* const* d_in, const int* in_sizes, int n_in,
                              void* d_out, int out_size, void* d_ws, size_t ws_size,
                              hipStream_t stream) {
  const float* x       = (const float*)d_in[0];
  // d_in[1] = edge_index: full 9-clique structure is compile-time, unused
  const float* W_in    = (const float*)d_in[2];
  const float* b_in    = (const float*)d_in[3];
  const float* W1_rel  = (const float*)d_in[4];
  const float* b1      = (const float*)d_in[5];
  const float* W1_root = (const float*)d_in[6];
  const float* W2_rel  = (const float*)d_in[7];
  const float* b2      = (const float*)d_in[8];
  const float* W2_root = (const float*)d_in[9];
  const float* Whead   = (const float*)d_in[10];
  const float* bhead   = (const float*)d_in[11];
  float* out = (float*)d_out;

  hipLaunchKernelGGL(prep_kernel, dim3(1), dim3(1024), 0, stream,
                     W_in, b_in, W1_rel, b1, W1_root, W2_rel, W2_root, Whead);
  hipLaunchKernelGGL(fused_kernel, dim3(NBLK), dim3(TPB), 0, stream,
                     x, b2, bhead, out);
}